// Round 3
// baseline (210.323 us; speedup 1.0000x reference)
//
#include <hip/hip_runtime.h>

// ---------- common helpers ----------
typedef __attribute__((ext_vector_type(8))) unsigned short ushort8v;
typedef __attribute__((ext_vector_type(8))) __bf16 bf16x8;
typedef __attribute__((ext_vector_type(4))) float floatx4;

__device__ __forceinline__ unsigned short f2b(float f) {
    unsigned u = __float_as_uint(f);
    unsigned r = u + 0x7fffu + ((u >> 16) & 1u);   // RNE
    return (unsigned short)(r >> 16);
}
__device__ __forceinline__ float b2f(unsigned short h) {
    return __uint_as_float(((unsigned)h) << 16);
}

// global -> LDS direct (16B/lane). Dest must be wave-uniform base + lane*16.
__device__ __forceinline__ void gload16(const unsigned short* g, unsigned short* l) {
    __builtin_amdgcn_global_load_lds(
        (const __attribute__((address_space(1))) unsigned int*)g,
        (__attribute__((address_space(3))) unsigned int*)l,
        16, 0, 0);
}

// ============================================================================
// Fragment-swizzled layout: tensor [T16][KC][16][8] bf16;
//   elem (t16, kc, l, e) = Mat[t16*16 + l][kc*8 + e]
// R11 post-mortem of R10: counted-vmcnt alone (1 block/CU, 120KB LDS) == R9's
// drain-every-step with 2 blocks/CU (48.4 vs 46.7us). The m114 cross-block
// overlap IS the dominant pipelining mechanism; counted-vmcnt only pays on
// top of it. This version has BOTH: 128x128 tile, 4 waves (2x2, 64x64/wave),
// BK=32, 4 x 16KB LDS buffers = 64KB -> 2 blocks/CU, depth-3 prefetch,
// steady vmcnt(12), tail 12/8/4/0. Plus bn-per-XCD swizzle: each XCD owns one
// 128-col panel -> B L2-resident (512/256KB), A streams with 3-step slack.
// ============================================================================

// ---------- fused prep ----------
// blocks [0,2048):      x (8192x2048 f32) -> A2x swizzled bf16 (KC=256)
// blocks [2048,4096):   W (2048x1023 f32) -> B2w swizzled bf16 (KC=256)
// blocks [4096,5120):   softmax(leaf_dist) -> B2p swizzled bf16 (KC=128), c>=1000 zero
__global__ __launch_bounds__(256) void prep_kernel(const float* __restrict__ x,
                                                   unsigned short* __restrict__ A2x,
                                                   const float* __restrict__ W,
                                                   unsigned short* __restrict__ B2w,
                                                   const float* __restrict__ ld_,
                                                   unsigned short* __restrict__ B2p) {
    __shared__ float tile[32 * 33];
    __shared__ float buf[1000];
    __shared__ float red[8];
    const int b = blockIdx.x, t = threadIdx.x;
    if (b < 2048) {                        // ---- cvt+swizzle x: quarter of a 16-row slab ----
        const int mt = b >> 2, kq = (b & 3) * 64;
        const int kco = t >> 4, l16 = t & 15;       // kco 0..15
        const float* xr0 = x + (size_t)(mt * 16 + l16) * 2048;
#pragma unroll
        for (int i = 0; i < 4; i++) {
            const int kc = kq + i * 16 + kco;
            const float* xr = xr0 + kc * 8;
            float4 v0 = *(const float4*)xr;
            float4 v1 = *(const float4*)(xr + 4);
            ushort8v o;
            o[0] = f2b(v0.x); o[1] = f2b(v0.y); o[2] = f2b(v0.z); o[3] = f2b(v0.w);
            o[4] = f2b(v1.x); o[5] = f2b(v1.y); o[6] = f2b(v1.z); o[7] = f2b(v1.w);
            *(ushort8v*)(A2x + ((size_t)(mt * 256 + kc) * 16 + l16) * 8) = o;
        }
    } else if (b < 4096) {                 // ---- transpose+swizzle W ----
        const int idx = b - 2048;
        const int n0 = (idx & 31) * 32, k0 = (idx >> 5) * 32;
        const int tx = t & 31, ty = t >> 5;
#pragma unroll
        for (int i = 0; i < 4; i++) {
            int k = k0 + ty + i * 8, n = n0 + tx;
            tile[(ty + i * 8) * 33 + tx] = (n < 1023) ? W[(size_t)k * 1023 + n] : 0.f;
        }
        __syncthreads();
#pragma unroll
        for (int i = 0; i < 4; i++) {
            int n = n0 + ty + i * 8, k = k0 + tx;
            size_t off = ((size_t)((n >> 4) * 256 + (k >> 3)) * 16 + (n & 15)) * 8 + (k & 7);
            B2w[off] = f2b(tile[tx * 33 + ty + i * 8]);
        }
    } else {                               // ---- softmax -> B2p swizzled (+zero pad) ----
        const int l0 = b - 4096;
        const float* r = ld_ + (size_t)l0 * 1000;
        float mx = -3.4e38f;
        for (int i = t; i < 1000; i += 256) { float v = r[i]; buf[i] = v; mx = fmaxf(mx, v); }
#pragma unroll
        for (int o = 32; o > 0; o >>= 1) mx = fmaxf(mx, __shfl_down(mx, o));
        if ((t & 63) == 0) red[t >> 6] = mx;
        __syncthreads();
        mx = fmaxf(fmaxf(red[0], red[1]), fmaxf(red[2], red[3]));
        float s = 0.f;
        for (int i = t; i < 1000; i += 256) { float e = __expf(buf[i] - mx); buf[i] = e; s += e; }
#pragma unroll
        for (int o = 32; o > 0; o >>= 1) s += __shfl_down(s, o);
        if ((t & 63) == 0) red[4 + (t >> 6)] = s;
        __syncthreads();
        float inv = 1.f / (red[4] + red[5] + red[6] + red[7]);
        for (int i = t; i < 1024; i += 256) {
            float pv = (i < 1000) ? buf[i] * inv : 0.f;
            size_t off = ((size_t)((i >> 4) * 128 + (l0 >> 3)) * 16 + (i & 15)) * 8 + (l0 & 7);
            B2p[off] = f2b(pv);
        }
    }
}

// ---------- pp: 8 rows per block (barriers amortized), writes A2p swizzled ----------
// LDS: d 8x1024 bf16 (16KB) + pa/pb 8x1024 f32 (64KB) = 80KB -> 2 blocks/CU.
__global__ __launch_bounds__(256) void pp_kernel(const unsigned short* __restrict__ dec,
                                                 unsigned short* __restrict__ A2p) {
    __shared__ unsigned short dsh[8 * 1024];
    __shared__ float pa[8 * 1024];
    __shared__ float pb[8 * 1024];
    const int t = threadIdx.x;
    const int r0 = blockIdx.x * 8;
    // load 8 rows of dec (16KB contiguous) as ushort8
    {
        const ushort8v* src = (const ushort8v*)(dec + (size_t)r0 * 1024);
        ushort8v* dst = (ushort8v*)dsh;
        for (int g = t; g < 1024; g += 256) dst[g] = src[g];
    }
    if (t < 8) pa[t * 1024] = 1.f;
    __syncthreads();
    float* cur = pa; float* nxt = pb;
    for (int dep = 0; dep < 10; dep++) {
        const int half = 1 << dep;
        const int len  = half << 1;
        const int total = len << 3;        // 8 rows
        for (int idx = t; idx < total; idx += 256) {
            const int r = idx >> (dep + 1);
            const int j = idx & (len - 1);
            int tt = j >> dep;
            int s  = j & (half - 1);
            int i2 = 2 * s + tt;
            int u  = i2 >> dep;
            int rr = i2 & (half - 1);
            float dv = b2f(dsh[r * 1024 + half - 1 + rr]);
            nxt[r * 1024 + j] = cur[r * 1024 + rr] * (u ? (1.f - dv) : dv);
        }
        __syncthreads();
        float* tmp = cur; cur = nxt; nxt = tmp;
    }
    // write swizzled A2p (KC=128): off(row, j)
    for (int i = t; i < 8192; i += 256) {
        const int r = i >> 10, j = i & 1023;
        const int rrow = r0 + r;
        size_t off = ((size_t)((rrow >> 4) * 128 + (j >> 3)) * 16 + (rrow & 15)) * 8 + (j & 7);
        A2p[off] = f2b(cur[r * 1024 + j]);
    }
}

// ---------- counted-vmcnt + 2-blocks/CU GEMM: 128x128 tile, 4 waves, 4 buffers ----------
// Buffer (16KB): A = 8 slabs x 4 kc-chunks = 32 chunks (8KB) at ushort [0..4096),
//                B = same at [4096..8192). 4 buffers = 64KB -> 2 blocks/CU.
// Stage = 4 gload16/thread (A0,A1,B0,B1); depth-3 ahead -> steady vmcnt(12).
// Step: vmcnt(N); s_barrier; ds_read 8 frags; lgkmcnt(0); s_barrier;
//       stage ks+4 into freed buffer; setprio(1); 16 MFMA; setprio(0).
// Tail: 4 peeled steps, vmcnt 12/8/4/0. No vmcnt(0) in main loop (T4).
// bn-per-XCD: xcd = bid&7 owns col-panel bn=xcd (B stays L2-resident).
#define VMW(N) asm volatile("s_waitcnt vmcnt(" #N ")" ::: "memory")

#define P4_STEP(ks_, b_, VM_, DOSTAGE_)                                             \
    {                                                                               \
        VMW(VM_);                                                                   \
        __builtin_amdgcn_s_barrier();                                               \
        __builtin_amdgcn_sched_barrier(0);                                          \
        const unsigned short* lA = &lds[(b_)][0];                                   \
        const unsigned short* lB = &lds[(b_)][4096];                                \
        bf16x8 af[4], bv[4];                                                        \
        _Pragma("unroll")                                                           \
        for (int m2 = 0; m2 < 4; m2++)                                              \
            af[m2] = __builtin_bit_cast(bf16x8,                                     \
                *(const ushort8v*)&lA[((wr * 4 + m2) * 4 + quad) * 128 + l16 * 8]); \
        _Pragma("unroll")                                                           \
        for (int n2 = 0; n2 < 4; n2++)                                              \
            bv[n2] = __builtin_bit_cast(bf16x8,                                     \
                *(const ushort8v*)&lB[((wc * 4 + n2) * 4 + quad) * 128 + l16 * 8]); \
        asm volatile("s_waitcnt lgkmcnt(0)" ::: "memory");                          \
        __builtin_amdgcn_sched_barrier(0);                                          \
        __builtin_amdgcn_s_barrier();                                               \
        __builtin_amdgcn_sched_barrier(0);                                          \
        if (DOSTAGE_) STAGE((ks_) + 4, (b_));                                       \
        __builtin_amdgcn_s_setprio(1);                                              \
        _Pragma("unroll")                                                           \
        for (int m2 = 0; m2 < 4; m2++)                                              \
            _Pragma("unroll")                                                       \
            for (int n2 = 0; n2 < 4; n2++)                                          \
                acc[m2][n2] = __builtin_amdgcn_mfma_f32_16x16x32_bf16(              \
                    af[m2], bv[n2], acc[m2][n2], 0, 0, 0);                          \
        __builtin_amdgcn_s_setprio(0);                                              \
    }

template <int EPI, int KC>
__global__ __launch_bounds__(256, 2) void gemm_p4(const unsigned short* __restrict__ A2,
                                                  const unsigned short* __restrict__ B2,
                                                  const float* __restrict__ bias,
                                                  unsigned short* __restrict__ obf,
                                                  float* __restrict__ of32, int ldo) {
    __shared__ unsigned short lds[4][8192];    // 4 bufs x 16KB = 64KB -> 2 blocks/CU

    const int tid  = threadIdx.x;
    const int lane = tid & 63;
    const int wave = tid >> 6;                 // 0..3
    const int quad = lane >> 4, l16 = lane & 15;
    const int wr = wave >> 1, wc = wave & 1;   // 2x2 wave grid, 64x64/wave

    const int bid = blockIdx.x;
    const int bn  = bid & 7;                   // one 128-col panel per XCD (L2-resident B)
    const int bm  = bid >> 3;                  // 0..63

    // stage map: issue i covers chunks c = i*16 + (tid>>4); slab = c>>2, kcq = c&3.
    // Per wave each issue is 4 chunks = 1KB contiguous; dest = wave-uniform + lane*16.
    const int c0  = tid >> 4;                  // 0..15
    const int sub = (tid & 15) * 8;            // ushort offset within 256B chunk
    const unsigned short* gA0 = A2 + ((size_t)(bm * 8 + (c0 >> 2))        * KC + (c0 & 3)) * 128 + sub;
    const unsigned short* gA1 = A2 + ((size_t)(bm * 8 + ((c0 + 16) >> 2)) * KC + (c0 & 3)) * 128 + sub;
    const unsigned short* gB0 = B2 + ((size_t)(bn * 8 + (c0 >> 2))        * KC + (c0 & 3)) * 128 + sub;
    const unsigned short* gB1 = B2 + ((size_t)(bn * 8 + ((c0 + 16) >> 2)) * KC + (c0 & 3)) * 128 + sub;
    const int dA0 = c0 * 128 + sub;            // ushort offsets in buffer
    const int dA1 = (c0 + 16) * 128 + sub;
    const int dB0 = 4096 + c0 * 128 + sub;
    const int dB1 = 4096 + (c0 + 16) * 128 + sub;

    floatx4 acc[4][4] = {};
    constexpr int nks = KC / 4;                // BK=32 -> 4 kc-chunks/step

    auto STAGE = [&](int ks, int b) {
        const size_t ko = (size_t)ks * 512;    // 4 chunks * 128 ushorts
        gload16(gA0 + ko, &lds[b][dA0]);
        gload16(gA1 + ko, &lds[b][dA1]);
        gload16(gB0 + ko, &lds[b][dB0]);
        gload16(gB1 + ko, &lds[b][dB1]);
    };

    // prologue: fill all 4 buffers (depth-3 ahead of first consume)
    STAGE(0, 0); STAGE(1, 1); STAGE(2, 2); STAGE(3, 3);

    for (int ks = 0; ks < nks - 4; ++ks) {
        P4_STEP(ks, ks & 3, 12, true);
    }
    P4_STEP(nks - 4, (nks - 4) & 3, 12, false);
    P4_STEP(nks - 3, (nks - 3) & 3, 8,  false);
    P4_STEP(nks - 2, (nks - 2) & 3, 4,  false);
    P4_STEP(nks - 1, (nks - 1) & 3, 0,  false);

    // ---- epilogue ----
    const int mt0 = bm * 8 + wr * 4;
    const int nt0 = bn * 8 + wc * 4;
#pragma unroll
    for (int n2 = 0; n2 < 4; n2++) {
        const int col = (nt0 + n2) * 16 + l16;
        float bbias = 0.f;
        if constexpr (EPI == 0) bbias = (col < 1023) ? bias[col] : 0.f;
#pragma unroll
        for (int m2 = 0; m2 < 4; m2++) {
            const int row0 = (mt0 + m2) * 16 + quad * 4;
#pragma unroll
            for (int r = 0; r < 4; r++) {
                float v = acc[m2][n2][r];
                if constexpr (EPI == 0) {
                    float sgm = 1.f / (1.f + __expf(-(v + bbias)));
                    obf[(size_t)(row0 + r) * ldo + col] = f2b(sgm);
                } else {
                    if (col < 1000) of32[(size_t)(row0 + r) * ldo + col] = v;
                }
            }
        }
    }
}

// ---------- host ----------
extern "C" void kernel_launch(void* const* d_in, const int* in_sizes, int n_in,
                              void* d_out, int out_size, void* d_ws, size_t ws_size,
                              hipStream_t stream) {
    const float* x   = (const float*)d_in[0];   // 8192x2048
    const float* W   = (const float*)d_in[1];   // 2048x1023
    const float* b   = (const float*)d_in[2];   // 1023
    const float* ldd = (const float*)d_in[3];   // 1024x1000
    float* out = (float*)d_out;                 // 8192x1000

    char* ws = (char*)d_ws;
    unsigned short* A2x = (unsigned short*)(ws);              // 33,554,432 B (swizzled x bf16)
    unsigned short* A2p = (unsigned short*)(ws);              // overlay: pp output (A2x dead by then)
    unsigned short* B2w = (unsigned short*)(ws + 33554432);   // 4,194,304 B (swizzled W^T)
    unsigned short* dec = (unsigned short*)(ws + 37748736);   // 16,777,216 B (row-major decisions)
    unsigned short* B2p = (unsigned short*)(ws + 54525952);   // 2,097,152 B (swizzled P^T)

    // prep: x-swizzle | W-transpose-swizzle | softmax->swizzle (independent)
    prep_kernel<<<5120, 256, 0, stream>>>(x, A2x, W, B2w, ldd, B2p);
    // decisions = sigmoid(x@W + b), row-major bf16 (cols padded to 1024)
    gemm_p4<0, 256><<<512, 256, 0, stream>>>(A2x, B2w, b, dec, nullptr, 1024);
    // pp (reference-literal order), 8 rows/block, writes swizzled A2p
    pp_kernel<<<1024, 256, 0, stream>>>(dec, A2p);
    // out = pp @ P
    gemm_p4<1, 128><<<512, 256, 0, stream>>>(A2p, B2p, nullptr, nullptr, out, 1000);
}

// Round 6
// 199.832 us; speedup vs baseline: 1.0525x; 1.0525x over previous
//
#include <hip/hip_runtime.h>

// ---------- common helpers ----------
typedef __attribute__((ext_vector_type(8))) unsigned short ushort8v;
typedef __attribute__((ext_vector_type(8))) __bf16 bf16x8;
typedef __attribute__((ext_vector_type(4))) float floatx4;

__device__ __forceinline__ unsigned short f2b(float f) {
    unsigned u = __float_as_uint(f);
    unsigned r = u + 0x7fffu + ((u >> 16) & 1u);   // RNE
    return (unsigned short)(r >> 16);
}
__device__ __forceinline__ float b2f(unsigned short h) {
    return __uint_as_float(((unsigned)h) << 16);
}

// global -> LDS direct (16B/lane). Dest must be wave-uniform base + lane*16.
__device__ __forceinline__ void gload16(const void* g, void* l) {
    __builtin_amdgcn_global_load_lds(
        (const __attribute__((address_space(1))) unsigned int*)g,
        (__attribute__((address_space(3))) unsigned int*)l,
        16, 0, 0);
}

// ============================================================================
// R14: fp8 FAILED accuracy (2.29e-4 > 7.5e-5; e4m3 ~4% RMS vs required ~0.5%
// rel) -> bf16 everywhere (absmax 3.05e-5 proven). Surviving model from
// R8-R11: gemm time = bytes-through-VMEM at ~20-26 B/cyc/CU, schedule- and
// path-invariant; only lever left is tile intensity (BM+BN)K*2/block.
// gemm1 -> 256x128 tile (256 blocks, 1/CU forced), 8 waves 4Mx2N, BK=32,
// 3-buffer ROTATING counted-vmcnt: stage at step top into the buffer freed
// two steps ago; steady vmcnt(6); 2 barriers/step; fine-grained (16 MFMA per
// step) per m201's proof that 1-blk/CU reaches ~20 B/cyc with this shape
// (R10's 12.9 B/cyc was coarse clustering, not 1-blk/CU per se).
// Staged: 512 -> 384 MB. gemm2 keeps R11's proven 128^2 (2 blk/CU, 256 MB).
// Fragment-swizzled layout: tensor [T16][KC][16][8] bf16;
//   elem (t16, kc, l, e) = Mat[t16*16 + l][kc*8 + e]
// ============================================================================

// ---------- fused prep ----------
// blocks [0,2048):      x (8192x2048 f32) -> A2x swizzled bf16 (KC=256)
// blocks [2048,4096):   W (2048x1023 f32) -> B2w swizzled bf16 (KC=256)
// blocks [4096,5120):   softmax(leaf_dist) -> B2p swizzled bf16 (KC=128), c>=1000 zero
__global__ __launch_bounds__(256) void prep_kernel(const float* __restrict__ x,
                                                   unsigned short* __restrict__ A2x,
                                                   const float* __restrict__ W,
                                                   unsigned short* __restrict__ B2w,
                                                   const float* __restrict__ ld_,
                                                   unsigned short* __restrict__ B2p) {
    __shared__ float tile[32 * 33];
    __shared__ float buf[1000];
    __shared__ float red[8];
    const int b = blockIdx.x, t = threadIdx.x;
    if (b < 2048) {                        // ---- cvt+swizzle x: quarter of a 16-row slab ----
        const int mt = b >> 2, kq = (b & 3) * 64;
        const int kco = t >> 4, l16 = t & 15;       // kco 0..15
        const float* xr0 = x + (size_t)(mt * 16 + l16) * 2048;
#pragma unroll
        for (int i = 0; i < 4; i++) {
            const int kc = kq + i * 16 + kco;
            const float* xr = xr0 + kc * 8;
            float4 v0 = *(const float4*)xr;
            float4 v1 = *(const float4*)(xr + 4);
            ushort8v o;
            o[0] = f2b(v0.x); o[1] = f2b(v0.y); o[2] = f2b(v0.z); o[3] = f2b(v0.w);
            o[4] = f2b(v1.x); o[5] = f2b(v1.y); o[6] = f2b(v1.z); o[7] = f2b(v1.w);
            *(ushort8v*)(A2x + ((size_t)(mt * 256 + kc) * 16 + l16) * 8) = o;
        }
    } else if (b < 4096) {                 // ---- transpose+swizzle W ----
        const int idx = b - 2048;
        const int n0 = (idx & 31) * 32, k0 = (idx >> 5) * 32;
        const int tx = t & 31, ty = t >> 5;
#pragma unroll
        for (int i = 0; i < 4; i++) {
            int k = k0 + ty + i * 8, n = n0 + tx;
            tile[(ty + i * 8) * 33 + tx] = (n < 1023) ? W[(size_t)k * 1023 + n] : 0.f;
        }
        __syncthreads();
#pragma unroll
        for (int i = 0; i < 4; i++) {
            int n = n0 + ty + i * 8, k = k0 + tx;
            size_t off = ((size_t)((n >> 4) * 256 + (k >> 3)) * 16 + (n & 15)) * 8 + (k & 7);
            B2w[off] = f2b(tile[tx * 33 + ty + i * 8]);
        }
    } else {                               // ---- softmax -> B2p swizzled (+zero pad) ----
        const int l0 = b - 4096;
        const float* r = ld_ + (size_t)l0 * 1000;
        float mx = -3.4e38f;
        for (int i = t; i < 1000; i += 256) { float v = r[i]; buf[i] = v; mx = fmaxf(mx, v); }
#pragma unroll
        for (int o = 32; o > 0; o >>= 1) mx = fmaxf(mx, __shfl_down(mx, o));
        if ((t & 63) == 0) red[t >> 6] = mx;
        __syncthreads();
        mx = fmaxf(fmaxf(red[0], red[1]), fmaxf(red[2], red[3]));
        float s = 0.f;
        for (int i = t; i < 1000; i += 256) { float e = __expf(buf[i] - mx); buf[i] = e; s += e; }
#pragma unroll
        for (int o = 32; o > 0; o >>= 1) s += __shfl_down(s, o);
        if ((t & 63) == 0) red[4 + (t >> 6)] = s;
        __syncthreads();
        float inv = 1.f / (red[4] + red[5] + red[6] + red[7]);
        for (int i = t; i < 1024; i += 256) {
            float pv = (i < 1000) ? buf[i] * inv : 0.f;
            size_t off = ((size_t)((i >> 4) * 128 + (l0 >> 3)) * 16 + (i & 15)) * 8 + (l0 & 7);
            B2p[off] = f2b(pv);
        }
    }
}

// ---------- pp: 8 rows per block (barriers amortized), writes A2p swizzled ----------
// LDS: d 8x1024 bf16 (16KB) + pa/pb 8x1024 f32 (64KB) = 80KB -> 2 blocks/CU.
__global__ __launch_bounds__(256) void pp_kernel(const unsigned short* __restrict__ dec,
                                                 unsigned short* __restrict__ A2p) {
    __shared__ unsigned short dsh[8 * 1024];
    __shared__ float pa[8 * 1024];
    __shared__ float pb[8 * 1024];
    const int t = threadIdx.x;
    const int r0 = blockIdx.x * 8;
    {
        const ushort8v* src = (const ushort8v*)(dec + (size_t)r0 * 1024);
        ushort8v* dst = (ushort8v*)dsh;
        for (int g = t; g < 1024; g += 256) dst[g] = src[g];
    }
    if (t < 8) pa[t * 1024] = 1.f;
    __syncthreads();
    float* cur = pa; float* nxt = pb;
    for (int dep = 0; dep < 10; dep++) {
        const int half = 1 << dep;
        const int len  = half << 1;
        const int total = len << 3;        // 8 rows
        for (int idx = t; idx < total; idx += 256) {
            const int r = idx >> (dep + 1);
            const int j = idx & (len - 1);
            int tt = j >> dep;
            int s  = j & (half - 1);
            int i2 = 2 * s + tt;
            int u  = i2 >> dep;
            int rr = i2 & (half - 1);
            float dv = b2f(dsh[r * 1024 + half - 1 + rr]);
            nxt[r * 1024 + j] = cur[r * 1024 + rr] * (u ? (1.f - dv) : dv);
        }
        __syncthreads();
        float* tmp = cur; cur = nxt; nxt = tmp;
    }
    // write swizzled A2p (KC=128): off(row, j)
    for (int i = t; i < 8192; i += 256) {
        const int r = i >> 10, j = i & 1023;
        const int rrow = r0 + r;
        size_t off = ((size_t)((rrow >> 4) * 128 + (j >> 3)) * 16 + (rrow & 15)) * 8 + (j & 7);
        A2p[off] = f2b(cur[r * 1024 + j]);
    }
}

#define VMW(N) asm volatile("s_waitcnt vmcnt(" #N ")" ::: "memory")

// ---------- gemm1: 256x128 tile, 8 waves, 3 rotating buffers, counted vmcnt ----------
// Buffer (24KB ushort[12288]): A = 16 slabs x 4 kc-chunks = 64 chunks (16KB) at [0..8192),
//                              B =  8 slabs x 4 kc-chunks = 32 chunks (8KB) at [8192..12288).
// Stage = 3 gload16/thread (A covers 64 chunks in 2 issues of 32, B in 1 issue of 32);
// LDS dest per issue = wave-uniform base + lane*16 (dA0 = tid*16 bytes).
// Step ks (cur = ks%3): stage ks+2 into (ks+2)%3 [the buffer whose reads finished at
// step ks-1]; vmcnt(6) -> ks's 3 loads done; s_barrier; ds_read 8 frags; lgkmcnt(0);
// setprio(1); 16 MFMA; setprio(0); s_barrier [protects buf ks%3 from step ks+1's stage].
// Tail: ks=62 vmcnt(3), ks=63 vmcnt(0). Steady state never drains (T4).
#define M1_STEP(ks_, CUR_, STG_, VM_, DOSTAGE_)                                       \
    {                                                                                 \
        if (DOSTAGE_) STAGE((ks_) + 2, (STG_));                                       \
        VMW(VM_);                                                                     \
        __builtin_amdgcn_s_barrier();                                                 \
        const unsigned short* lA = &lds[(CUR_)][0];                                   \
        const unsigned short* lB = &lds[(CUR_)][8192];                                \
        bf16x8 af[4], bv[4];                                                          \
        _Pragma("unroll")                                                             \
        for (int m2 = 0; m2 < 4; m2++)                                                \
            af[m2] = __builtin_bit_cast(bf16x8,                                       \
                *(const ushort8v*)&lA[((wr * 4 + m2) * 4 + quad) * 128 + l16 * 8]);   \
        _Pragma("unroll")                                                             \
        for (int n2 = 0; n2 < 4; n2++)                                                \
            bv[n2] = __builtin_bit_cast(bf16x8,                                       \
                *(const ushort8v*)&lB[((wc * 4 + n2) * 4 + quad) * 128 + l16 * 8]);   \
        asm volatile("s_waitcnt lgkmcnt(0)" ::: "memory");                            \
        __builtin_amdgcn_sched_barrier(0);                                            \
        __builtin_amdgcn_s_setprio(1);                                                \
        _Pragma("unroll")                                                             \
        for (int m2 = 0; m2 < 4; m2++)                                                \
            _Pragma("unroll")                                                         \
            for (int n2 = 0; n2 < 4; n2++)                                            \
                acc[m2][n2] = __builtin_amdgcn_mfma_f32_16x16x32_bf16(                \
                    af[m2], bv[n2], acc[m2][n2], 0, 0, 0);                            \
        __builtin_amdgcn_s_setprio(0);                                                \
        __builtin_amdgcn_s_barrier();                                                 \
    }

__global__ __launch_bounds__(512, 1) void gemm_m1(const unsigned short* __restrict__ A2,
                                                  const unsigned short* __restrict__ B2,
                                                  const float* __restrict__ bias,
                                                  unsigned short* __restrict__ obf) {
    constexpr int KC = 256;                    // kc-chunks (2048 elems)
    __shared__ unsigned short lds[3][12288];   // 3 bufs x 24KB = 72KB -> 1 block/CU

    const int tid  = threadIdx.x;              // 0..511
    const int lane = tid & 63;
    const int wave = tid >> 6;                 // 0..7
    const int quad = lane >> 4, l16 = lane & 15;
    const int wr = wave >> 1, wc = wave & 1;   // 4M x 2N wave grid, 64x64/wave

    const int bid = blockIdx.x;                // 256 blocks
    const int xcd = bid & 7;
    const int j   = bid >> 3;                  // 0..31
    const int bm  = xcd * 4 + (j & 3);         // 0..31 (256-row tiles; 4MB A + 4MB B per XCD)
    const int bn  = j >> 2;                    // 0..7  (128-col tiles)

    // stage map: issue covers chunks c = base + (tid>>4); slab = c>>2, kcq = c&3.
    const int cA  = tid >> 4;                  // 0..31
    const int sub = (tid & 15) * 8;            // ushort offset within 256B chunk
    const unsigned short* gA0 = A2 + ((size_t)(bm * 16 + (cA >> 2))        * KC + (cA & 3)) * 128 + sub;
    const unsigned short* gA1 = A2 + ((size_t)(bm * 16 + ((cA + 32) >> 2)) * KC + (cA & 3)) * 128 + sub;
    const unsigned short* gB0 = B2 + ((size_t)(bn * 8  + (cA >> 2))        * KC + (cA & 3)) * 128 + sub;
    const int dA0 = cA * 128 + sub;            // = tid*8 ushorts = tid*16 B (wave-uniform + lane*16)
    const int dA1 = (cA + 32) * 128 + sub;
    const int dB0 = 8192 + cA * 128 + sub;

    floatx4 acc[4][4] = {};
    constexpr int nks = KC / 4;                // 64 steps (BK=32)

    auto STAGE = [&](int ks, int b) {
        const size_t ko = (size_t)ks * 512;    // 4 kc-chunks * 128 ushorts
        gload16(gA0 + ko, &lds[b][dA0]);
        gload16(gA1 + ko, &lds[b][dA1]);
        gload16(gB0 + ko, &lds[b][dB0]);
    };

    // prologue: depth-2 prefetch
    STAGE(0, 0); STAGE(1, 1);

    int c0 = 0, c1 = 1, c2 = 2;
    for (int ks = 0; ks < nks - 2; ++ks) {
        M1_STEP(ks, c0, c2, 6, true);
        int tmp = c0; c0 = c1; c1 = c2; c2 = tmp;
    }
    M1_STEP(nks - 2, c0, c2, 3, false);
    { int tmp = c0; c0 = c1; c1 = c2; c2 = tmp; }
    M1_STEP(nks - 1, c0, c2, 0, false);

    // ---- epilogue: sigmoid(acc + bias[col]) -> bf16, ldo=1024 ----
    const int mt0 = bm * 16 + wr * 4;
    const int nt0 = bn * 8  + wc * 4;
#pragma unroll
    for (int n2 = 0; n2 < 4; n2++) {
        const int col = (nt0 + n2) * 16 + l16;
        const float bbias = (col < 1023) ? bias[col] : 0.f;
#pragma unroll
        for (int m2 = 0; m2 < 4; m2++) {
            const int row0 = (mt0 + m2) * 16 + quad * 4;
#pragma unroll
            for (int r = 0; r < 4; r++) {
                float sgm = 1.f / (1.f + __expf(-(acc[m2][n2][r] + bbias)));
                obf[(size_t)(row0 + r) * 1024 + col] = f2b(sgm);
            }
        }
    }
}

// ---------- gemm2: R11's proven 128x128, 4 waves, 4 buffers, counted vmcnt ----------
#define P4_STEP(ks_, b_, VM_, DOSTAGE_)                                             \
    {                                                                               \
        VMW(VM_);                                                                   \
        __builtin_amdgcn_s_barrier();                                               \
        __builtin_amdgcn_sched_barrier(0);                                          \
        const unsigned short* lA = &lds[(b_)][0];                                   \
        const unsigned short* lB = &lds[(b_)][4096];                                \
        bf16x8 af[4], bv[4];                                                        \
        _Pragma("unroll")                                                           \
        for (int m2 = 0; m2 < 4; m2++)                                              \
            af[m2] = __builtin_bit_cast(bf16x8,                                     \
                *(const ushort8v*)&lA[((wr * 4 + m2) * 4 + quad) * 128 + l16 * 8]); \
        _Pragma("unroll")                                                           \
        for (int n2 = 0; n2 < 4; n2++)                                              \
            bv[n2] = __builtin_bit_cast(bf16x8,                                     \
                *(const ushort8v*)&lB[((wc * 4 + n2) * 4 + quad) * 128 + l16 * 8]); \
        asm volatile("s_waitcnt lgkmcnt(0)" ::: "memory");                          \
        __builtin_amdgcn_sched_barrier(0);                                          \
        __builtin_amdgcn_s_barrier();                                               \
        __builtin_amdgcn_sched_barrier(0);                                          \
        if (DOSTAGE_) STAGE((ks_) + 4, (b_));                                       \
        __builtin_amdgcn_s_setprio(1);                                              \
        _Pragma("unroll")                                                           \
        for (int m2 = 0; m2 < 4; m2++)                                              \
            _Pragma("unroll")                                                       \
            for (int n2 = 0; n2 < 4; n2++)                                          \
                acc[m2][n2] = __builtin_amdgcn_mfma_f32_16x16x32_bf16(              \
                    af[m2], bv[n2], acc[m2][n2], 0, 0, 0);                          \
        __builtin_amdgcn_s_setprio(0);                                              \
    }

template <int KC>
__global__ __launch_bounds__(256, 2) void gemm_p4(const unsigned short* __restrict__ A2,
                                                  const unsigned short* __restrict__ B2,
                                                  float* __restrict__ of32, int ldo) {
    __shared__ unsigned short lds[4][8192];    // 4 bufs x 16KB = 64KB -> 2 blocks/CU

    const int tid  = threadIdx.x;
    const int lane = tid & 63;
    const int wave = tid >> 6;                 // 0..3
    const int quad = lane >> 4, l16 = lane & 15;
    const int wr = wave >> 1, wc = wave & 1;   // 2x2 wave grid, 64x64/wave

    const int bid = blockIdx.x;
    const int xcd = bid & 7;
    const int j   = bid >> 3;                  // 0..63
    const int bm  = xcd * 8 + (j & 7);         // 128-row tile idx 0..63
    const int bn  = j >> 3;                    // 0..7

    const int c0  = tid >> 4;                  // 0..15
    const int sub = (tid & 15) * 8;
    const unsigned short* gA0 = A2 + ((size_t)(bm * 8 + (c0 >> 2))        * KC + (c0 & 3)) * 128 + sub;
    const unsigned short* gA1 = A2 + ((size_t)(bm * 8 + ((c0 + 16) >> 2)) * KC + (c0 & 3)) * 128 + sub;
    const unsigned short* gB0 = B2 + ((size_t)(bn * 8 + (c0 >> 2))        * KC + (c0 & 3)) * 128 + sub;
    const unsigned short* gB1 = B2 + ((size_t)(bn * 8 + ((c0 + 16) >> 2)) * KC + (c0 & 3)) * 128 + sub;
    const int dA0 = c0 * 128 + sub;
    const int dA1 = (c0 + 16) * 128 + sub;
    const int dB0 = 4096 + c0 * 128 + sub;
    const int dB1 = 4096 + (c0 + 16) * 128 + sub;

    floatx4 acc[4][4] = {};
    constexpr int nks = KC / 4;

    auto STAGE = [&](int ks, int b) {
        const size_t ko = (size_t)ks * 512;
        gload16(gA0 + ko, &lds[b][dA0]);
        gload16(gA1 + ko, &lds[b][dA1]);
        gload16(gB0 + ko, &lds[b][dB0]);
        gload16(gB1 + ko, &lds[b][dB1]);
    };

    STAGE(0, 0); STAGE(1, 1); STAGE(2, 2); STAGE(3, 3);

    for (int ks = 0; ks < nks - 4; ++ks) {
        P4_STEP(ks, ks & 3, 12, true);
    }
    P4_STEP(nks - 4, (nks - 4) & 3, 12, false);
    P4_STEP(nks - 3, (nks - 3) & 3, 8,  false);
    P4_STEP(nks - 2, (nks - 2) & 3, 4,  false);
    P4_STEP(nks - 1, (nks - 1) & 3, 0,  false);

    // ---- epilogue: f32, col<1000 ----
    const int mt0 = bm * 8 + wr * 4;
    const int nt0 = bn * 8 + wc * 4;
#pragma unroll
    for (int n2 = 0; n2 < 4; n2++) {
        const int col = (nt0 + n2) * 16 + l16;
#pragma unroll
        for (int m2 = 0; m2 < 4; m2++) {
            const int row0 = (mt0 + m2) * 16 + quad * 4;
#pragma unroll
            for (int r = 0; r < 4; r++) {
                if (col < 1000) of32[(size_t)(row0 + r) * ldo + col] = acc[m2][n2][r];
            }
        }
    }
}

// ---------- host ----------
extern "C" void kernel_launch(void* const* d_in, const int* in_sizes, int n_in,
                              void* d_out, int out_size, void* d_ws, size_t ws_size,
                              hipStream_t stream) {
    const float* x   = (const float*)d_in[0];   // 8192x2048
    const float* W   = (const float*)d_in[1];   // 2048x1023
    const float* b   = (const float*)d_in[2];   // 1023
    const float* ldd = (const float*)d_in[3];   // 1024x1000
    float* out = (float*)d_out;                 // 8192x1000

    char* ws = (char*)d_ws;
    unsigned short* A2x = (unsigned short*)(ws);              // 33,554,432 B (swizzled x bf16)
    unsigned short* A2p = (unsigned short*)(ws);              // overlay: pp output (A2x dead by then)
    unsigned short* B2w = (unsigned short*)(ws + 33554432);   // 4,194,304 B (swizzled W^T)
    unsigned short* dec = (unsigned short*)(ws + 37748736);   // 16,777,216 B (row-major decisions)
    unsigned short* B2p = (unsigned short*)(ws + 54525952);   // 2,097,152 B (swizzled P^T)

    // prep: x-swizzle | W-transpose-swizzle | softmax->swizzle (independent)
    prep_kernel<<<5120, 256, 0, stream>>>(x, A2x, W, B2w, ldd, B2p);
    // decisions = sigmoid(x@W + b), row-major bf16 (cols padded to 1024)
    gemm_m1<<<256, 512, 0, stream>>>(A2x, B2w, b, dec);
    // pp (reference-literal order), 8 rows/block, writes swizzled A2p
    pp_kernel<<<1024, 256, 0, stream>>>(dec, A2p);
    // out = pp @ P
    gemm_p4<128><<<512, 256, 0, stream>>>(A2p, B2p, out, 1000);
}

// Round 7
// 198.749 us; speedup vs baseline: 1.0582x; 1.0055x over previous
//
#include <hip/hip_runtime.h>

// ---------- common helpers ----------
typedef __attribute__((ext_vector_type(8))) unsigned short ushort8v;
typedef __attribute__((ext_vector_type(4))) unsigned short ushort4v;
typedef __attribute__((ext_vector_type(8))) __bf16 bf16x8;
typedef __attribute__((ext_vector_type(4))) float floatx4;

__device__ __forceinline__ unsigned short f2b(float f) {
    unsigned u = __float_as_uint(f);
    unsigned r = u + 0x7fffu + ((u >> 16) & 1u);   // RNE
    return (unsigned short)(r >> 16);
}
__device__ __forceinline__ float b2f(unsigned short h) {
    return __uint_as_float(((unsigned)h) << 16);
}

// global -> LDS direct (16B/lane). Dest must be wave-uniform base + lane*16.
__device__ __forceinline__ void gload16(const void* g, void* l) {
    __builtin_amdgcn_global_load_lds(
        (const __attribute__((address_space(1))) unsigned int*)g,
        (__attribute__((address_space(3))) unsigned int*)l,
        16, 0, 0);
}

// ============================================================================
// R15. Staged-bytes model FALSIFIED in R14: 384MB staged (1 blk/CU) == 512MB
// (2 blk/CU) == 45-47us. Rate scales with co-resident staging pipelines
// (~14 B/cyc/CU per block, saturating ~18-21 at 2-3 blocks; m103: 21.7 at 3)
// -> latency*concurrency limit, not bandwidth. gemm1 at 45.3us (758 TF
// effective) is this structure's ceiling for the 512-block grid geometry;
// FROZEN after 4 schedule nulls. This round attacks the 154.5us non-gemm1
// residual (prep/pp/gemm2/gaps, all individually <45.1):
//  - pp: levels 0-5 composed analytically per thread (6 factors collected
//    backward, multiplied FORWARD -> bitwise-identical); barriers 11 -> 5;
//    A2p stores vectorized ushort4 (swizzle keeps j%4 runs contiguous).
//  - prep: W-transpose stores vectorized ushort4 (4 consecutive k in one
//    8B slot); x-read remapped row-linear (128B contiguous per lane).
//  - gemm1/gemm2 UNCHANGED (one variable class per round).
// Fragment-swizzled layout: tensor [T16][KC][16][8] bf16;
//   elem (t16, kc, l, e) = Mat[t16*16 + l][kc*8 + e]
// ============================================================================

// ---------- fused prep ----------
// blocks [0,2048):      x (8192x2048 f32) -> A2x swizzled bf16 (KC=256)
// blocks [2048,4096):   W (2048x1023 f32) -> B2w swizzled bf16 (KC=256)
// blocks [4096,5120):   softmax(leaf_dist) -> B2p swizzled bf16 (KC=128), c>=1000 zero
__global__ __launch_bounds__(256) void prep_kernel(const float* __restrict__ x,
                                                   unsigned short* __restrict__ A2x,
                                                   const float* __restrict__ W,
                                                   unsigned short* __restrict__ B2w,
                                                   const float* __restrict__ ld_,
                                                   unsigned short* __restrict__ B2p) {
    __shared__ float tile[32 * 33];
    __shared__ float buf[1000];
    __shared__ float red[8];
    const int b = blockIdx.x, t = threadIdx.x;
    if (b < 2048) {                        // ---- cvt+swizzle x: quarter of a 16-row slab ----
        const int mt = b >> 2, kq = (b & 3) * 64;
        const int l16 = t >> 4;            // row 0..15
        const int sg  = t & 15;            // 4 consecutive kc-chunks (128B contiguous read)
        const float* xr = x + (size_t)(mt * 16 + l16) * 2048 + (size_t)(kq + sg * 4) * 8;
#pragma unroll
        for (int c = 0; c < 4; c++) {
            float4 v0 = *(const float4*)(xr + c * 8);
            float4 v1 = *(const float4*)(xr + c * 8 + 4);
            ushort8v o;
            o[0] = f2b(v0.x); o[1] = f2b(v0.y); o[2] = f2b(v0.z); o[3] = f2b(v0.w);
            o[4] = f2b(v1.x); o[5] = f2b(v1.y); o[6] = f2b(v1.z); o[7] = f2b(v1.w);
            const int kc = kq + sg * 4 + c;
            *(ushort8v*)(A2x + ((size_t)(mt * 256 + kc) * 16 + l16) * 8) = o;
        }
    } else if (b < 4096) {                 // ---- transpose+swizzle W, ushort4 stores ----
        const int idx = b - 2048;
        const int n0 = (idx & 31) * 32, k0 = (idx >> 5) * 32;
        const int tx = t & 31, ty = t >> 5;
#pragma unroll
        for (int i = 0; i < 4; i++) {
            int k = k0 + ty + i * 8, n = n0 + tx;
            tile[(ty + i * 8) * 33 + tx] = (n < 1023) ? W[(size_t)k * 1023 + n] : 0.f;
        }
        __syncthreads();
        {
            const int tx2 = t & 31, ky = t >> 5;        // ky 0..7 -> 4 consecutive k
            const int n = n0 + tx2;
            const int k = k0 + ky * 4;                  // (k&7) in {0,4}: ushort4-aligned
            ushort4v o;
#pragma unroll
            for (int e = 0; e < 4; e++) o[e] = f2b(tile[(ky * 4 + e) * 33 + tx2]);
            size_t off = ((size_t)((n >> 4) * 256 + (k >> 3)) * 16 + (n & 15)) * 8 + (k & 7);
            *(ushort4v*)(B2w + off) = o;
        }
    } else {                               // ---- softmax -> B2p swizzled (+zero pad) ----
        const int l0 = b - 4096;
        const float* r = ld_ + (size_t)l0 * 1000;
        float mx = -3.4e38f;
        for (int i = t; i < 1000; i += 256) { float v = r[i]; buf[i] = v; mx = fmaxf(mx, v); }
#pragma unroll
        for (int o = 32; o > 0; o >>= 1) mx = fmaxf(mx, __shfl_down(mx, o));
        if ((t & 63) == 0) red[t >> 6] = mx;
        __syncthreads();
        mx = fmaxf(fmaxf(red[0], red[1]), fmaxf(red[2], red[3]));
        float s = 0.f;
        for (int i = t; i < 1000; i += 256) { float e = __expf(buf[i] - mx); buf[i] = e; s += e; }
#pragma unroll
        for (int o = 32; o > 0; o >>= 1) s += __shfl_down(s, o);
        if ((t & 63) == 0) red[4 + (t >> 6)] = s;
        __syncthreads();
        float inv = 1.f / (red[4] + red[5] + red[6] + red[7]);
        for (int i = t; i < 1024; i += 256) {
            float pv = (i < 1000) ? buf[i] * inv : 0.f;
            size_t off = ((size_t)((i >> 4) * 128 + (l0 >> 3)) * 16 + (i & 15)) * 8 + (l0 & 7);
            B2p[off] = f2b(pv);
        }
    }
}

// ---------- pp: 8 rows/block; levels 0-5 direct (no barriers), 6-9 iterative ----------
// LDS: dsh 16KB + pa/pb 64KB = 80KB -> 2 blocks/CU. Barriers: 5 total (was 11).
__global__ __launch_bounds__(256) void pp_kernel(const unsigned short* __restrict__ dec,
                                                 unsigned short* __restrict__ A2p) {
    __shared__ unsigned short dsh[8 * 1024];
    __shared__ float pa[8 * 1024];
    __shared__ float pb[8 * 1024];
    const int t = threadIdx.x;
    const int r0 = blockIdx.x * 8;
    {
        const ushort8v* src = (const ushort8v*)(dec + (size_t)r0 * 1024);
        ushort8v* dst = (ushort8v*)dsh;
        for (int g = t; g < 1024; g += 256) dst[g] = src[g];
    }
    __syncthreads();
    // ---- direct levels 0..5: level-6 state (64 vals/row), 2 per thread ----
    // Backward index-walk collects factors fac[dep]; forward multiply ->
    // bitwise-identical to the iterative reference order.
    {
        const int r  = t >> 5;             // 0..7
        const int jb = (t & 31) * 2;
        const unsigned short* dr = &dsh[r * 1024];
#pragma unroll
        for (int e = 0; e < 2; e++) {
            int idx = jb + e;
            float fac[6];
#pragma unroll
            for (int dep = 5; dep >= 0; --dep) {
                const int half = 1 << dep;
                const int tt = idx >> dep;
                const int s  = idx & (half - 1);
                const int i2 = 2 * s + tt;
                const int u  = i2 >> dep;
                const int rr = i2 & (half - 1);
                const float dv = b2f(dr[half - 1 + rr]);
                fac[dep] = u ? (1.f - dv) : dv;
                idx = rr;
            }
            float prod = fac[0];
#pragma unroll
            for (int dep = 1; dep < 6; dep++) prod *= fac[dep];
            pa[r * 1024 + jb + e] = prod;
        }
    }
    __syncthreads();
    float* cur = pa; float* nxt = pb;
    for (int dep = 6; dep < 10; dep++) {
        const int half = 1 << dep;
        const int len  = half << 1;
        const int total = len << 3;        // 8 rows
        for (int idx = t; idx < total; idx += 256) {
            const int r = idx >> (dep + 1);
            const int j = idx & (len - 1);
            int tt = j >> dep;
            int s  = j & (half - 1);
            int i2 = 2 * s + tt;
            int u  = i2 >> dep;
            int rr = i2 & (half - 1);
            float dv = b2f(dsh[r * 1024 + half - 1 + rr]);
            nxt[r * 1024 + j] = cur[r * 1024 + rr] * (u ? (1.f - dv) : dv);
        }
        __syncthreads();
        float* tmp = cur; cur = nxt; nxt = tmp;
    }
    // ---- vectorized swizzled write: 32 outputs/thread as 8x ushort4 ----
    {
        const int r  = t >> 5;             // 0..7
        const int jb = (t & 31) * 32;
        const int rrow = r0 + r;
        const float* cr = &cur[r * 1024];
        const size_t rbase = (size_t)(rrow >> 4) * 128 * 128 + (size_t)(rrow & 15) * 8;
#pragma unroll
        for (int g = 0; g < 8; g++) {
            const int j = jb + g * 4;      // (j&7) in {0,4}: ushort4-aligned slot
            ushort4v o;
            o[0] = f2b(cr[j]); o[1] = f2b(cr[j + 1]);
            o[2] = f2b(cr[j + 2]); o[3] = f2b(cr[j + 3]);
            size_t off = rbase + (size_t)(j >> 3) * 128 + (j & 7);
            *(ushort4v*)(A2p + off) = o;
        }
    }
}

#define VMW(N) asm volatile("s_waitcnt vmcnt(" #N ")" ::: "memory")

// ---------- gemm1: 256x128 tile, 8 waves, 3 rotating buffers, counted vmcnt ----------
#define M1_STEP(ks_, CUR_, STG_, VM_, DOSTAGE_)                                       \
    {                                                                                 \
        if (DOSTAGE_) STAGE((ks_) + 2, (STG_));                                       \
        VMW(VM_);                                                                     \
        __builtin_amdgcn_s_barrier();                                                 \
        const unsigned short* lA = &lds[(CUR_)][0];                                   \
        const unsigned short* lB = &lds[(CUR_)][8192];                                \
        bf16x8 af[4], bv[4];                                                          \
        _Pragma("unroll")                                                             \
        for (int m2 = 0; m2 < 4; m2++)                                                \
            af[m2] = __builtin_bit_cast(bf16x8,                                       \
                *(const ushort8v*)&lA[((wr * 4 + m2) * 4 + quad) * 128 + l16 * 8]);   \
        _Pragma("unroll")                                                             \
        for (int n2 = 0; n2 < 4; n2++)                                                \
            bv[n2] = __builtin_bit_cast(bf16x8,                                       \
                *(const ushort8v*)&lB[((wc * 4 + n2) * 4 + quad) * 128 + l16 * 8]);   \
        asm volatile("s_waitcnt lgkmcnt(0)" ::: "memory");                            \
        __builtin_amdgcn_sched_barrier(0);                                            \
        __builtin_amdgcn_s_setprio(1);                                                \
        _Pragma("unroll")                                                             \
        for (int m2 = 0; m2 < 4; m2++)                                                \
            _Pragma("unroll")                                                         \
            for (int n2 = 0; n2 < 4; n2++)                                            \
                acc[m2][n2] = __builtin_amdgcn_mfma_f32_16x16x32_bf16(                \
                    af[m2], bv[n2], acc[m2][n2], 0, 0, 0);                            \
        __builtin_amdgcn_s_setprio(0);                                                \
        __builtin_amdgcn_s_barrier();                                                 \
    }

__global__ __launch_bounds__(512, 1) void gemm_m1(const unsigned short* __restrict__ A2,
                                                  const unsigned short* __restrict__ B2,
                                                  const float* __restrict__ bias,
                                                  unsigned short* __restrict__ obf) {
    constexpr int KC = 256;
    __shared__ unsigned short lds[3][12288];   // 3 bufs x 24KB = 72KB -> 1 block/CU

    const int tid  = threadIdx.x;
    const int lane = tid & 63;
    const int wave = tid >> 6;                 // 0..7
    const int quad = lane >> 4, l16 = lane & 15;
    const int wr = wave >> 1, wc = wave & 1;   // 4M x 2N wave grid, 64x64/wave

    const int bid = blockIdx.x;                // 256 blocks
    const int xcd = bid & 7;
    const int j   = bid >> 3;                  // 0..31
    const int bm  = xcd * 4 + (j & 3);         // 0..31 (256-row tiles)
    const int bn  = j >> 2;                    // 0..7  (128-col tiles)

    const int cA  = tid >> 4;                  // 0..31
    const int sub = (tid & 15) * 8;
    const unsigned short* gA0 = A2 + ((size_t)(bm * 16 + (cA >> 2))        * KC + (cA & 3)) * 128 + sub;
    const unsigned short* gA1 = A2 + ((size_t)(bm * 16 + ((cA + 32) >> 2)) * KC + (cA & 3)) * 128 + sub;
    const unsigned short* gB0 = B2 + ((size_t)(bn * 8  + (cA >> 2))        * KC + (cA & 3)) * 128 + sub;
    const int dA0 = cA * 128 + sub;
    const int dA1 = (cA + 32) * 128 + sub;
    const int dB0 = 8192 + cA * 128 + sub;

    floatx4 acc[4][4] = {};
    constexpr int nks = KC / 4;                // 64 steps (BK=32)

    auto STAGE = [&](int ks, int b) {
        const size_t ko = (size_t)ks * 512;
        gload16(gA0 + ko, &lds[b][dA0]);
        gload16(gA1 + ko, &lds[b][dA1]);
        gload16(gB0 + ko, &lds[b][dB0]);
    };

    STAGE(0, 0); STAGE(1, 1);

    int c0 = 0, c1 = 1, c2 = 2;
    for (int ks = 0; ks < nks - 2; ++ks) {
        M1_STEP(ks, c0, c2, 6, true);
        int tmp = c0; c0 = c1; c1 = c2; c2 = tmp;
    }
    M1_STEP(nks - 2, c0, c2, 3, false);
    { int tmp = c0; c0 = c1; c1 = c2; c2 = tmp; }
    M1_STEP(nks - 1, c0, c2, 0, false);

    // ---- epilogue: sigmoid(acc + bias[col]) -> bf16, ldo=1024 ----
    const int mt0 = bm * 16 + wr * 4;
    const int nt0 = bn * 8  + wc * 4;
#pragma unroll
    for (int n2 = 0; n2 < 4; n2++) {
        const int col = (nt0 + n2) * 16 + l16;
        const float bbias = (col < 1023) ? bias[col] : 0.f;
#pragma unroll
        for (int m2 = 0; m2 < 4; m2++) {
            const int row0 = (mt0 + m2) * 16 + quad * 4;
#pragma unroll
            for (int r = 0; r < 4; r++) {
                float sgm = 1.f / (1.f + __expf(-(acc[m2][n2][r] + bbias)));
                obf[(size_t)(row0 + r) * 1024 + col] = f2b(sgm);
            }
        }
    }
}

// ---------- gemm2: 128x128, 4 waves, 4 buffers, counted vmcnt (R11-proven) ----------
#define P4_STEP(ks_, b_, VM_, DOSTAGE_)                                             \
    {                                                                               \
        VMW(VM_);                                                                   \
        __builtin_amdgcn_s_barrier();                                               \
        __builtin_amdgcn_sched_barrier(0);                                          \
        const unsigned short* lA = &lds[(b_)][0];                                   \
        const unsigned short* lB = &lds[(b_)][4096];                                \
        bf16x8 af[4], bv[4];                                                        \
        _Pragma("unroll")                                                           \
        for (int m2 = 0; m2 < 4; m2++)                                              \
            af[m2] = __builtin_bit_cast(bf16x8,                                     \
                *(const ushort8v*)&lA[((wr * 4 + m2) * 4 + quad) * 128 + l16 * 8]); \
        _Pragma("unroll")                                                           \
        for (int n2 = 0; n2 < 4; n2++)                                              \
            bv[n2] = __builtin_bit_cast(bf16x8,                                     \
                *(const ushort8v*)&lB[((wc * 4 + n2) * 4 + quad) * 128 + l16 * 8]); \
        asm volatile("s_waitcnt lgkmcnt(0)" ::: "memory");                          \
        __builtin_amdgcn_sched_barrier(0);                                          \
        __builtin_amdgcn_s_barrier();                                               \
        __builtin_amdgcn_sched_barrier(0);                                          \
        if (DOSTAGE_) STAGE((ks_) + 4, (b_));                                       \
        __builtin_amdgcn_s_setprio(1);                                              \
        _Pragma("unroll")                                                           \
        for (int m2 = 0; m2 < 4; m2++)                                              \
            _Pragma("unroll")                                                       \
            for (int n2 = 0; n2 < 4; n2++)                                          \
                acc[m2][n2] = __builtin_amdgcn_mfma_f32_16x16x32_bf16(              \
                    af[m2], bv[n2], acc[m2][n2], 0, 0, 0);                          \
        __builtin_amdgcn_s_setprio(0);                                              \
    }

template <int KC>
__global__ __launch_bounds__(256, 2) void gemm_p4(const unsigned short* __restrict__ A2,
                                                  const unsigned short* __restrict__ B2,
                                                  float* __restrict__ of32, int ldo) {
    __shared__ unsigned short lds[4][8192];

    const int tid  = threadIdx.x;
    const int lane = tid & 63;
    const int wave = tid >> 6;
    const int quad = lane >> 4, l16 = lane & 15;
    const int wr = wave >> 1, wc = wave & 1;

    const int bid = blockIdx.x;
    const int xcd = bid & 7;
    const int j   = bid >> 3;
    const int bm  = xcd * 8 + (j & 7);
    const int bn  = j >> 3;

    const int c0  = tid >> 4;
    const int sub = (tid & 15) * 8;
    const unsigned short* gA0 = A2 + ((size_t)(bm * 8 + (c0 >> 2))        * KC + (c0 & 3)) * 128 + sub;
    const unsigned short* gA1 = A2 + ((size_t)(bm * 8 + ((c0 + 16) >> 2)) * KC + (c0 & 3)) * 128 + sub;
    const unsigned short* gB0 = B2 + ((size_t)(bn * 8 + (c0 >> 2))        * KC + (c0 & 3)) * 128 + sub;
    const unsigned short* gB1 = B2 + ((size_t)(bn * 8 + ((c0 + 16) >> 2)) * KC + (c0 & 3)) * 128 + sub;
    const int dA0 = c0 * 128 + sub;
    const int dA1 = (c0 + 16) * 128 + sub;
    const int dB0 = 4096 + c0 * 128 + sub;
    const int dB1 = 4096 + (c0 + 16) * 128 + sub;

    floatx4 acc[4][4] = {};
    constexpr int nks = KC / 4;

    auto STAGE = [&](int ks, int b) {
        const size_t ko = (size_t)ks * 512;
        gload16(gA0 + ko, &lds[b][dA0]);
        gload16(gA1 + ko, &lds[b][dA1]);
        gload16(gB0 + ko, &lds[b][dB0]);
        gload16(gB1 + ko, &lds[b][dB1]);
    };

    STAGE(0, 0); STAGE(1, 1); STAGE(2, 2); STAGE(3, 3);

    for (int ks = 0; ks < nks - 4; ++ks) {
        P4_STEP(ks, ks & 3, 12, true);
    }
    P4_STEP(nks - 4, (nks - 4) & 3, 12, false);
    P4_STEP(nks - 3, (nks - 3) & 3, 8,  false);
    P4_STEP(nks - 2, (nks - 2) & 3, 4,  false);
    P4_STEP(nks - 1, (nks - 1) & 3, 0,  false);

    const int mt0 = bm * 8 + wr * 4;
    const int nt0 = bn * 8 + wc * 4;
#pragma unroll
    for (int n2 = 0; n2 < 4; n2++) {
        const int col = (nt0 + n2) * 16 + l16;
#pragma unroll
        for (int m2 = 0; m2 < 4; m2++) {
            const int row0 = (mt0 + m2) * 16 + quad * 4;
#pragma unroll
            for (int r = 0; r < 4; r++) {
                if (col < 1000) of32[(size_t)(row0 + r) * ldo + col] = acc[m2][n2][r];
            }
        }
    }
}

// ---------- host ----------
extern "C" void kernel_launch(void* const* d_in, const int* in_sizes, int n_in,
                              void* d_out, int out_size, void* d_ws, size_t ws_size,
                              hipStream_t stream) {
    const float* x   = (const float*)d_in[0];   // 8192x2048
    const float* W   = (const float*)d_in[1];   // 2048x1023
    const float* b   = (const float*)d_in[2];   // 1023
    const float* ldd = (const float*)d_in[3];   // 1024x1000
    float* out = (float*)d_out;                 // 8192x1000

    char* ws = (char*)d_ws;
    unsigned short* A2x = (unsigned short*)(ws);              // 33,554,432 B (swizzled x bf16)
    unsigned short* A2p = (unsigned short*)(ws);              // overlay: pp output (A2x dead by then)
    unsigned short* B2w = (unsigned short*)(ws + 33554432);   // 4,194,304 B (swizzled W^T)
    unsigned short* dec = (unsigned short*)(ws + 37748736);   // 16,777,216 B (row-major decisions)
    unsigned short* B2p = (unsigned short*)(ws + 54525952);   // 2,097,152 B (swizzled P^T)

    // prep: x-swizzle | W-transpose-swizzle | softmax->swizzle (independent)
    prep_kernel<<<5120, 256, 0, stream>>>(x, A2x, W, B2w, ldd, B2p);
    // decisions = sigmoid(x@W + b), row-major bf16 (cols padded to 1024)
    gemm_m1<<<256, 512, 0, stream>>>(A2x, B2w, b, dec);
    // pp (reference-literal order), 8 rows/block, writes swizzled A2p
    pp_kernel<<<1024, 256, 0, stream>>>(dec, A2p);
    // out = pp @ P
    gemm_p4<128><<<512, 256, 0, stream>>>(A2p, B2p, out, 1000);
}